// Round 10
// baseline (98.562 us; speedup 1.0000x reference)
//
#include <hip/hip_runtime.h>

typedef _Float16 h8 __attribute__((ext_vector_type(8)));
typedef _Float16 h4 __attribute__((ext_vector_type(4)));
typedef _Float16 h2 __attribute__((ext_vector_type(2)));
typedef float f4 __attribute__((ext_vector_type(4)));

#define NT 7        // n-tiles: 112 output features (100 real)
#define KC 4        // k-chunks of 32: k=0..99 real, k=100 -> t, k=101 -> 1
#define HSTRIDE 104 // halves per comb row (208 B, 16B-aligned)

// TWO WAVES PER TREE (subtree split). Levels 8..5: wave w owns the half-tree
// whose comb rows live in panel [64w, 64w+64) — fully disjoint, barrier-free.
// Ring compaction keeps each level's output inside the panel: a tile writes
// its 8 comb rows into the first 8 rows it just read (same-wave DS is
// in-order, so read-before-write is safe); level (8-e) output row for comb m'
// is (8<<e)*(m'>>3) + (m'&7). One __syncthreads, then wave0 runs levels 4..0
// (<=16 nodes, reads both panels) + projection. 1024 blocks x 2 waves =
// 2 waves/SIMD -> cross-block latency hiding the 1-wave version lacked.
__global__ __launch_bounds__(128, 1)
void grnn_fused(const float* __restrict__ times,
                const float* __restrict__ Qw,
                const float* __restrict__ Qb,
                const float* __restrict__ Ww,
                const float* __restrict__ Wb,
                const float* __restrict__ Pw,
                const float* __restrict__ Pb,
                float* __restrict__ out)
{
  __shared__ __align__(16) _Float16 Cs[128][HSTRIDE]; // 26624 B
  __shared__ __align__(16) _Float16 trash[512];       // sink for dead lanes
  __shared__ __align__(4)  _Float16 ts_fold[512];     // heap t[0..510] as f16
  __shared__ __align__(4)  h2 tsp[256];               // leaf pair (t[511+2n], t[512+2n])

  const int tid  = threadIdx.x;        // 0..127
  const int wave = tid >> 6;           // 0,1
  const int lane = tid & 63;
  const int l15  = lane & 15;
  const int kg   = lane >> 4;
  const int tree = blockIdx.x;
  const int PB   = wave << 6;          // panel base row

  // ---- persistent W fragments (B[k][n]=Ww[n][k]); fold k=100 -> Qw,
  //      k=101 -> Qb+Wb. Both waves carry the full 7-nt set. ----
  h8 wf[NT][KC];
  #pragma unroll
  for (int nt = 0; nt < NT; ++nt) {
    const int r = nt * 16 + l15;
    #pragma unroll
    for (int kc = 0; kc < KC; ++kc) {
      h8 v;
      #pragma unroll
      for (int j = 0; j < 8; ++j) v[j] = (_Float16)0.f;
      if (r < 100) {
        const int kb = kc * 32 + kg * 8;
        if (kc < 3) {
          const f4 w0 = *(const f4*)&Ww[r * 100 + kb];
          const f4 w1 = *(const f4*)&Ww[r * 100 + kb + 4];
          #pragma unroll
          for (int j = 0; j < 4; ++j) {
            v[j]     = (_Float16)w0[j];
            v[j + 4] = (_Float16)w1[j];
          }
        } else if (kg == 0) {
          const f4 w0 = *(const f4*)&Ww[r * 100 + 96];
          #pragma unroll
          for (int j = 0; j < 4; ++j) v[j] = (_Float16)w0[j];
          v[4] = (_Float16)Qw[r];            // k=100
          v[5] = (_Float16)(Qb[r] + Wb[r]);  // k=101
        }
      }
      wf[nt][kc] = v;
    }
  }

  // ---- packed leaf Q vectors ----
  h8 qwp[KC], qbp[KC];
  #pragma unroll
  for (int kc = 0; kc < KC; ++kc) {
    const int kb = kc * 32 + kg * 8;
    #pragma unroll
    for (int j = 0; j < 8; ++j) {
      const int ix = kb + j;
      qwp[kc][j] = (ix < 100) ? (_Float16)Qw[ix] : (_Float16)0.f;
      qbp[kc][j] = (ix < 100) ? (_Float16)Qb[ix] : (_Float16)0.f;
    }
  }

  // ---- cooperative staging (128 threads), then the one barrier ----
  {
    const float* tg = times + tree * 1023;
    #pragma unroll
    for (int q = 0; q < 4; ++q) {
      const int ix = tid + 128 * q;
      if (ix < 511) ts_fold[ix] = (_Float16)tg[ix];
    }
    #pragma unroll
    for (int q = 0; q < 2; ++q) {
      const int pr = tid + 128 * q;    // 0..255
      tsp[pr] = (h2){(_Float16)tg[511 + 2 * pr], (_Float16)tg[512 + 2 * pr]};
    }
  }
  __syncthreads();

// MFMA tile + epilogue: cvt->relu->DPP quad_perm(1,0,3,2) sibling add ->
// even-l15 lanes store comb row RW; dead lanes (odd l15, nt6 kg!=0) -> trash.
#define DO_MT(AFR, RW) do {                                                   \
    const int rw_ = (RW);                                                     \
    _Float16* pv_ = (l15 & 1) ? &trash[lane * 4] : &Cs[rw_][kg * 4];          \
    _Float16* p6_ = kg ? &trash[lane * 4] : pv_;                              \
    _Pragma("unroll")                                                         \
    for (int nt_ = 0; nt_ < NT; ++nt_) {                                      \
      f4 acc_ = {0.f, 0.f, 0.f, 0.f};                                         \
      _Pragma("unroll")                                                       \
      for (int kc_ = 0; kc_ < KC; ++kc_)                                      \
        acc_ = __builtin_amdgcn_mfma_f32_16x16x32_f16(wf[nt_][kc_],           \
                                                      AFR[kc_], acc_, 0,0,0); \
      h2 c0_ = {(_Float16)acc_[0], (_Float16)acc_[1]};                        \
      h2 c1_ = {(_Float16)acc_[2], (_Float16)acc_[3]};                        \
      const h2 z2_ = {(_Float16)0.f, (_Float16)0.f};                          \
      c0_ = __builtin_elementwise_max(c0_, z2_);                              \
      c1_ = __builtin_elementwise_max(c1_, z2_);                              \
      int d0_ = __builtin_amdgcn_mov_dpp(__builtin_bit_cast(int, c0_),        \
                                         0xB1, 0xF, 0xF, true);               \
      int d1_ = __builtin_amdgcn_mov_dpp(__builtin_bit_cast(int, c1_),        \
                                         0xB1, 0xF, 0xF, true);               \
      c0_ = c0_ + __builtin_bit_cast(h2, d0_);                                \
      c1_ = c1_ + __builtin_bit_cast(h2, d1_);                                \
      h4 hv_ = {c0_[0], c0_[1], c1_[0], c1_[1]};                              \
      *(h4*)((nt_ == 6 ? p6_ : pv_) + nt_ * 16) = hv_;                        \
    }                                                                         \
  } while (0)

// Root: no sibling add; only l15==0 stores, into row 0.
#define DO_MT_ROOT(AFR) do {                                                  \
    _Float16* pv_ = (l15 == 0) ? &Cs[0][kg * 4] : &trash[lane * 4];           \
    _Float16* p6_ = kg ? &trash[lane * 4] : pv_;                              \
    _Pragma("unroll")                                                         \
    for (int nt_ = 0; nt_ < NT; ++nt_) {                                      \
      f4 acc_ = {0.f, 0.f, 0.f, 0.f};                                         \
      _Pragma("unroll")                                                       \
      for (int kc_ = 0; kc_ < KC; ++kc_)                                      \
        acc_ = __builtin_amdgcn_mfma_f32_16x16x32_f16(wf[nt_][kc_],           \
                                                      AFR[kc_], acc_, 0,0,0); \
      h2 c0_ = {(_Float16)acc_[0], (_Float16)acc_[1]};                        \
      h2 c1_ = {(_Float16)acc_[2], (_Float16)acc_[3]};                        \
      const h2 z2_ = {(_Float16)0.f, (_Float16)0.f};                          \
      c0_ = __builtin_elementwise_max(c0_, z2_);                              \
      c1_ = __builtin_elementwise_max(c1_, z2_);                              \
      h4 hv_ = {c0_[0], c0_[1], c1_[0], c1_[1]};                              \
      *(h4*)((nt_ == 6 ? p6_ : pv_) + nt_ * 16) = hv_;                        \
    }                                                                         \
  } while (0)

// af for one tile: comb row ROW, fold slot from ts_fold[TSI] (kg!=0 lanes'
// af[3] garbage is harmless — multiplies wf==0).
#define LOAD_AFR(AFR, ROW, TSI) do {                                          \
    const int row_ = (ROW);                                                   \
    AFR[0] = *(const h8*)&Cs[row_][kg * 8];                                   \
    AFR[1] = *(const h8*)&Cs[row_][32 + kg * 8];                              \
    AFR[2] = *(const h8*)&Cs[row_][64 + kg * 8];                              \
    h4 lo_ = *(const h4*)&Cs[row_][96];                                       \
    h4 hi_ = {ts_fold[TSI], (_Float16)1.f, (_Float16)0.f, (_Float16)0.f};     \
    AFR[3] = __builtin_shufflevector(lo_, hi_, 0, 1, 2, 3, 4, 5, 6, 7);       \
  } while (0)

  // ---- level 8: 8 tiles per wave (global nodes 128w+16i+l15); leaf comb in
  //      packed f16 VALU; writes panel rows dense 8i..8i+7 ----
  h2 tpv[8]; _Float16 tfv[8];
  #pragma unroll
  for (int i = 0; i < 8; ++i) {
    tpv[i] = tsp[128 * wave + 16 * i + l15];
    tfv[i] = ts_fold[255 + 128 * wave + 16 * i + l15];
  }
  const h8 z8 = {(_Float16)0.f, (_Float16)0.f, (_Float16)0.f, (_Float16)0.f,
                 (_Float16)0.f, (_Float16)0.f, (_Float16)0.f, (_Float16)0.f};
  #pragma unroll
  for (int i = 0; i < 8; ++i) {
    const _Float16 t0 = tpv[i][0], t1 = tpv[i][1];
    h8 afl[KC];
    #pragma unroll
    for (int kc = 0; kc < KC; ++kc) {
      h8 a = qwp[kc] * t0 + qbp[kc];
      h8 b = qwp[kc] * t1 + qbp[kc];
      a = __builtin_elementwise_max(a, z8);
      b = __builtin_elementwise_max(b, z8);
      afl[kc] = a + b;
    }
    afl[3][4] = tfv[i];
    afl[3][5] = (_Float16)1.f;
    DO_MT(afl, PB + 8 * i + (l15 >> 1));
  }

  // ---- levels 7,6,5 per wave: explicit ring-compacted pipeline ----
  {
    h8 af[KC], afn[KC];
    // L7 tile j: read rows PB+16j+l15 (dense), write PB+16j+(l15>>1);
    // fold heap idx 127 + 64w + 16j + l15.
    LOAD_AFR(af, PB + l15, 127 + 64 * wave + l15);                    // (7,0)
    LOAD_AFR(afn, PB + 16 + l15, 127 + 64 * wave + 16 + l15);         // (7,1)
    DO_MT(af, PB + (l15 >> 1));
    #pragma unroll
    for (int c = 0; c < KC; ++c) af[c] = afn[c];
    LOAD_AFR(afn, PB + 32 + l15, 127 + 64 * wave + 32 + l15);         // (7,2)
    DO_MT(af, PB + 16 + (l15 >> 1));
    #pragma unroll
    for (int c = 0; c < KC; ++c) af[c] = afn[c];
    LOAD_AFR(afn, PB + 48 + l15, 127 + 64 * wave + 48 + l15);         // (7,3)
    DO_MT(af, PB + 32 + (l15 >> 1));
    #pragma unroll
    for (int c = 0; c < KC; ++c) af[c] = afn[c];
    // (6,0): reads PB+{0..7,16..23} — written by (7,0),(7,1); disjoint from
    // pending (7,2)/(7,3) writes.
    LOAD_AFR(afn, PB + 16 * (l15 >> 3) + (l15 & 7), 63 + 32 * wave + l15);
    DO_MT(af, PB + 48 + (l15 >> 1));                                  // (7,3)
    #pragma unroll
    for (int c = 0; c < KC; ++c) af[c] = afn[c];
    // (6,1): reads PB+{32..39,48..55} — (7,3) wrote 48..55 earlier in program
    // order; pending (6,0) writes PB+0..7 disjoint.
    LOAD_AFR(afn, PB + 32 + 16 * (l15 >> 3) + (l15 & 7),
             63 + 32 * wave + 16 + l15);
    DO_MT(af, PB + (l15 >> 1));                                       // (6,0)
    #pragma unroll
    for (int c = 0; c < KC; ++c) af[c] = afn[c];
    DO_MT(af, PB + 32 + (l15 >> 1));                                  // (6,1)
    // (5,0): reads PB+{0..7,32..39} — needs (6,1)'s rows 32..39 -> late load.
    LOAD_AFR(af, PB + 32 * (l15 >> 3) + (l15 & 7), 31 + 16 * wave + l15);
    DO_MT(af, PB + (l15 >> 1));                                       // (5,0)
  }
  __syncthreads();

  // ---- tail: wave0 only. L4 reads both panels (rows 0..7 / 64..71). ----
  if (wave == 0) {
    h8 af[KC];
    LOAD_AFR(af, (l15 < 8) ? l15 : (56 + l15), 15 + l15);             // L4
    DO_MT(af, (l15 >> 1));
    #pragma unroll 1
    for (int d = 3; d >= 1; --d) {                                    // L3..L1
      LOAD_AFR(af, l15, (1 << d) - 1 + l15);
      DO_MT(af, (l15 >> 1));
    }
    LOAD_AFR(af, l15, l15);                                           // root
    DO_MT_ROOT(af);

    // ---- projection: out[p] = root . Pw[p] + Pb[p], p<5 ----
    #pragma unroll 1
    for (int p = 0; p < 5; ++p) {
      float v = (float)Cs[0][lane] * Pw[p * 100 + lane];
      if (lane < 36) v += (float)Cs[0][64 + lane] * Pw[p * 100 + 64 + lane];
      v += __shfl_xor(v, 32, 64);
      v += __shfl_xor(v, 16, 64);
      v += __shfl_xor(v, 8, 64);
      v += __shfl_xor(v, 4, 64);
      v += __shfl_xor(v, 2, 64);
      v += __shfl_xor(v, 1, 64);
      if (lane == 0) out[tree * 5 + p] = v + Pb[p];
    }
  }
#undef DO_MT
#undef DO_MT_ROOT
#undef LOAD_AFR
}

extern "C" void kernel_launch(void* const* d_in, const int* in_sizes, int n_in,
                              void* d_out, int out_size, void* d_ws, size_t ws_size,
                              hipStream_t stream) {
  (void)n_in; (void)out_size; (void)d_ws; (void)ws_size;
  const float* times = (const float*)d_in[0];
  const float* Qw = (const float*)d_in[1];
  const float* Qb = (const float*)d_in[2];
  const float* Ww = (const float*)d_in[3];
  const float* Wb = (const float*)d_in[4];
  const float* Pw = (const float*)d_in[5];
  const float* Pb = (const float*)d_in[6];
  float* outp = (float*)d_out;
  const int B = in_sizes[0] / 1023;   // 1024 trees, 2 waves each
  grnn_fused<<<dim3(B), dim3(128), 0, stream>>>(times, Qw, Qb, Ww, Wb, Pw, Pb, outp);
}